// Round 6
// baseline (70.701 us; speedup 1.0000x reference)
//
#include <hip/hip_runtime.h>
#include <hip/hip_bf16.h>
#include <cstddef>
#include <cstdint>

// LinearAttention fused pipeline, MI355X gfx950.
// x:[16,64,64,128] f32, w_qkv:[128,384], w_out:[128,128], b_out/g_ln/b_ln:[128]
// Pipeline (4 kernels):
//   K1 k_transpose_wqkv: w_qkv -> w_qkv^T bf16
//   K2 k_kv_ctx: (R3-proven) per 128-token tile: Bk/Bv LDS-staged, k,v GEMMs
//      (shared A-frags), exp(k) -> LDS transpose -> per-head ctx partial + ksum.
//   K3 k_weff64: per (b,h): reduce ctx partials, ctxn=ctx/ksum,
//      W_eff^T[b][c][hd] = sum_e ctxn[d][e]*wout[h*32+e][c]  (bf16)
//   K4 k_qout2: FUSED q GEMM (transposed orientation: C[d][token], so softmax
//      over d needs only 2 shuffles) + softmax -> LDS -> GEMM2(W_eff) + bias
//      + LayerNorm -> out. Zero barriers (waves self-contained), no qs in HBM.
// Lesson R5: the q-path cost was the softmax epilogue structure (64 shfl
// chains + 2B scattered stores + qs HBM round-trip), NOT global B-gathers.

typedef __attribute__((ext_vector_type(8))) short short8_t;
typedef __attribute__((ext_vector_type(4))) float f32x4;

#define SCALE_Q 0.17677669529663687f
#define EPS_LN 1e-5f

__device__ __forceinline__ unsigned short f2bf(float f) {
  union { float f; unsigned u; } v; v.f = f;
  unsigned r = (v.u + 0x7FFFu + ((v.u >> 16) & 1u)) >> 16;
  return (unsigned short)r;
}
__device__ __forceinline__ float bf2f(unsigned short u) {
  union { float f; unsigned u; } v; v.u = ((unsigned)u) << 16;
  return v.f;
}

// pack 8 f32 -> 8 bf16 by truncation: 4x v_perm_b32
__device__ __forceinline__ short8_t trunc8(float4 lo, float4 hi) {
  union { float4 f; unsigned u[4]; } a, b;
  union { unsigned u[4]; short8_t s; } r;
  a.f = lo; b.f = hi;
  r.u[0] = __builtin_amdgcn_perm(a.u[1], a.u[0], 0x07060302);
  r.u[1] = __builtin_amdgcn_perm(a.u[3], a.u[2], 0x07060302);
  r.u[2] = __builtin_amdgcn_perm(b.u[1], b.u[0], 0x07060302);
  r.u[3] = __builtin_amdgcn_perm(b.u[3], b.u[2], 0x07060302);
  return r.s;
}
// pack 2 f32 -> 2 bf16 (truncate) into one dword
__device__ __forceinline__ unsigned pack2(float f0, float f1) {
  union { float f; unsigned u; } a, b; a.f = f0; b.f = f1;
  return __builtin_amdgcn_perm(b.u, a.u, 0x07060302);
}

// ---------------- K1: transpose + bf16 convert w_qkv [128][384] -> [384][128]
__global__ void k_transpose_wqkv(const float* __restrict__ w,
                                 unsigned short* __restrict__ wT) {
  int c = blockIdx.x * 4 + (threadIdx.x >> 6);   // 96 blocks -> c < 384
  int l = threadIdx.x & 63;
  float f0 = w[(size_t)(2 * l) * 384 + c];
  float f1 = w[(size_t)(2 * l + 1) * 384 + c];
  unsigned p = (unsigned)f2bf(f0) | ((unsigned)f2bf(f1) << 16);
  ((unsigned*)(wT + (size_t)c * 128))[l] = p;
}

// ---------------- K2: k+v GEMMs + in-tile ctx partial (R3-proven structure)
__global__ __launch_bounds__(256, 2)
void k_kv_ctx(const float* __restrict__ x, const unsigned short* __restrict__ wT,
              float* __restrict__ ctxp, float* __restrict__ ksump) {
  __shared__ short Bk[128][136];  // k weights; later reused as ekT[d][token]
  __shared__ short Bv[128][136];  // v weights; later reused as vT[e][token]

  int tid = threadIdx.x;
  int rb = blockIdx.x;
  int rowBase = rb * 128;

  { // stage Bk, Bv from wT parts 1 and 2 (coalesced)
    const unsigned short* wk = wT + (size_t)1 * 128 * 128;
    const unsigned short* wv2 = wT + (size_t)2 * 128 * 128;
#pragma unroll
    for (int i = 0; i < 8; ++i) {
      int idx = i * 256 + tid;
      int n = idx >> 4;
      int k8 = (idx & 15) << 3;
      *(short8_t*)&Bk[n][k8] = *(const short8_t*)(wk + (size_t)n * 128 + k8);
      *(short8_t*)&Bv[n][k8] = *(const short8_t*)(wv2 + (size_t)n * 128 + k8);
    }
  }

  int lane = tid & 63;
  int wv = tid >> 6;
  int wr = wv >> 1, wc = wv & 1;
  int lr = lane & 15;
  int kg = lane >> 4;

  // A fragments: load x f32 and convert once; reused by both GEMMs
  short8_t abf[4][4];  // [kk][mf]
  {
    const float* ap = x + (size_t)(rowBase + wr * 64 + lr) * 128 + kg * 8;
#pragma unroll
    for (int mf = 0; mf < 4; ++mf) {
      const float* r = ap + (size_t)mf * 16 * 128;
#pragma unroll
      for (int kk = 0; kk < 4; ++kk)
        abf[kk][mf] = trunc8(*(const float4*)(r + kk * 32),
                             *(const float4*)(r + kk * 32 + 4));
    }
  }
  __syncthreads();  // Bk/Bv staged

  // k GEMM -> exp -> packed bf16 (4 tokens per uint2)
  uint2 ekp[4][4], vp[4][4];
  {
    f32x4 acc[4][4] = {};
#pragma unroll
    for (int kk = 0; kk < 4; ++kk) {
      short8_t bf[4];
#pragma unroll
      for (int nf = 0; nf < 4; ++nf)
        bf[nf] = *(const short8_t*)&Bk[wc * 64 + nf * 16 + lr][kk * 32 + kg * 8];
#pragma unroll
      for (int mf = 0; mf < 4; ++mf)
#pragma unroll
        for (int nf = 0; nf < 4; ++nf)
          acc[mf][nf] = __builtin_amdgcn_mfma_f32_16x16x32_bf16(abf[kk][mf], bf[nf], acc[mf][nf], 0, 0, 0);
    }
#pragma unroll
    for (int mf = 0; mf < 4; ++mf)
#pragma unroll
      for (int nf = 0; nf < 4; ++nf) {
        unsigned s0 = f2bf(__expf(acc[mf][nf][0])), s1 = f2bf(__expf(acc[mf][nf][1]));
        unsigned s2 = f2bf(__expf(acc[mf][nf][2])), s3 = f2bf(__expf(acc[mf][nf][3]));
        ekp[mf][nf].x = s0 | (s1 << 16);
        ekp[mf][nf].y = s2 | (s3 << 16);
      }
  }
  // v GEMM -> packed bf16
  {
    f32x4 acc[4][4] = {};
#pragma unroll
    for (int kk = 0; kk < 4; ++kk) {
      short8_t bf[4];
#pragma unroll
      for (int nf = 0; nf < 4; ++nf)
        bf[nf] = *(const short8_t*)&Bv[wc * 64 + nf * 16 + lr][kk * 32 + kg * 8];
#pragma unroll
      for (int mf = 0; mf < 4; ++mf)
#pragma unroll
        for (int nf = 0; nf < 4; ++nf)
          acc[mf][nf] = __builtin_amdgcn_mfma_f32_16x16x32_bf16(abf[kk][mf], bf[nf], acc[mf][nf], 0, 0, 0);
    }
#pragma unroll
    for (int mf = 0; mf < 4; ++mf)
#pragma unroll
      for (int nf = 0; nf < 4; ++nf) {
        unsigned s0 = f2bf(acc[mf][nf][0]), s1 = f2bf(acc[mf][nf][1]);
        unsigned s2 = f2bf(acc[mf][nf][2]), s3 = f2bf(acc[mf][nf][3]);
        vp[mf][nf].x = s0 | (s1 << 16);
        vp[mf][nf].y = s2 | (s3 << 16);
      }
  }
  __syncthreads();  // all waves done reading Bk/Bv

  // transposed LDS write: ekT[channel][token], vT[channel][token]
  short (*ekT)[136] = Bk;
  short (*vT)[136] = Bv;
#pragma unroll
  for (int mf = 0; mf < 4; ++mf) {
    int t0 = wr * 64 + mf * 16 + kg * 4;  // 4 consecutive tokens
#pragma unroll
    for (int nf = 0; nf < 4; ++nf) {
      int col = wc * 64 + nf * 16 + lr;
      *(uint2*)&ekT[col][t0] = ekp[mf][nf];
      *(uint2*)&vT[col][t0] = vp[mf][nf];
    }
  }
  __syncthreads();

  // per-head ctx MFMA: wave wv = head h. ctx[d][e] = sum_n ekT[d][n]*vT[e][n]
  {
    int h = wv;
    f32x4 c2[2][2] = {};
#pragma unroll
    for (int kk = 0; kk < 4; ++kk) {
      short8_t a2[2], b2[2];
#pragma unroll
      for (int m2 = 0; m2 < 2; ++m2)
        a2[m2] = *(const short8_t*)&ekT[h * 32 + m2 * 16 + lr][kk * 32 + kg * 8];
#pragma unroll
      for (int n2 = 0; n2 < 2; ++n2)
        b2[n2] = *(const short8_t*)&vT[h * 32 + n2 * 16 + lr][kk * 32 + kg * 8];
#pragma unroll
      for (int m2 = 0; m2 < 2; ++m2)
#pragma unroll
        for (int n2 = 0; n2 < 2; ++n2)
          c2[m2][n2] = __builtin_amdgcn_mfma_f32_16x16x32_bf16(a2[m2], b2[n2], c2[m2][n2], 0, 0, 0);
    }
    float* cp = ctxp + ((size_t)rb * 4 + h) * 1024;
#pragma unroll
    for (int m2 = 0; m2 < 2; ++m2)
#pragma unroll
      for (int n2 = 0; n2 < 2; ++n2)
#pragma unroll
        for (int j = 0; j < 4; ++j)
          cp[(m2 * 16 + kg * 4 + j) * 32 + n2 * 16 + lr] = c2[m2][n2][j];
  }

  // ksum partial: threads 0..127 sum ekT[channel][0..127]
  if (tid < 128) {
    float s = 0;
#pragma unroll
    for (int t8 = 0; t8 < 128; t8 += 8) {
      short8_t v8 = *(const short8_t*)&ekT[tid][t8];
#pragma unroll
      for (int i = 0; i < 8; ++i) s += bf2f((unsigned short)v8[i]);
    }
    ksump[(size_t)rb * 128 + tid] = s;
  }
}

// ---------------- K3: per (b,h) reduce partials + build W_eff^T cols
// grid 64. weffT[b][c][h*32+d] = sum_e (ctx[d][e]/ksum[d]) * wout[h*32+e][c]
__global__ __launch_bounds__(256, 4)
void k_weff64(const float* __restrict__ ctxp, const float* __restrict__ ksump,
              const float* __restrict__ wout, unsigned short* __restrict__ weffT) {
  __shared__ float wo[32][128];  // wout rows h*32+e
  __shared__ float cn[32][32];   // ctxn[d][e]
  __shared__ float ksh[32];
  int tid = threadIdx.x;
  int b = blockIdx.x >> 2, h = blockIdx.x & 3;

#pragma unroll
  for (int i = 0; i < 16; ++i) {
    int idx = i * 256 + tid;
    int e = idx >> 7, jj = idx & 127;
    wo[e][jj] = wout[(h * 32 + e) * 128 + jj];
  }
  if (tid < 32) {
    float s = 0;
    for (int c = 0; c < 32; ++c)
      s += ksump[(size_t)(b * 32 + c) * 128 + h * 32 + tid];
    ksh[tid] = s;
  }
  __syncthreads();
#pragma unroll
  for (int i = 0; i < 4; ++i) {
    int idx = i * 256 + tid;
    int d = idx >> 5, e = idx & 31;
    float s = 0;
    for (int c = 0; c < 32; ++c)
      s += ctxp[((size_t)(b * 32 + c) * 4 + h) * 1024 + idx];
    cn[d][e] = s / ksh[d];
  }
  __syncthreads();

  int j = tid >> 1, dg = tid & 1;
  unsigned short acc16[16];
#pragma unroll
  for (int dd = 0; dd < 16; ++dd) {
    int d = dg * 16 + dd;
    float s = 0;
#pragma unroll
    for (int e = 0; e < 32; ++e) s += cn[d][e] * wo[e][j];
    acc16[dd] = f2bf(s);
  }
  unsigned short* outp = weffT + (size_t)b * 16384 + j * 128 + h * 32 + dg * 16;
  *(short8_t*)outp = *(short8_t*)&acc16[0];
  *(short8_t*)(outp + 8) = *(short8_t*)&acc16[8];
}

// ---------------- K4: fused q GEMM(transposed) + softmax + GEMM2 + bias + LN
// grid 1024 (64 tokens/block), 4 waves; wave = 16 tokens, fully independent.
// Zero barriers: each wave writes & reads only its own 16 LDS rows.
__global__ __launch_bounds__(256, 4)
void k_qout2(const float* __restrict__ x, const unsigned short* __restrict__ wT,
             const unsigned short* __restrict__ weffT,
             const float* __restrict__ b_out, const float* __restrict__ g_ln,
             const float* __restrict__ b_ln, float* __restrict__ out) {
  __shared__ short QS[64][132];  // softmaxed q, [token][hd], +4 pad

  int tid = threadIdx.x;
  int lane = tid & 63;
  int w = tid >> 6;
  int lr = lane & 15;
  int kg = lane >> 4;
  int tokBase = blockIdx.x * 64;
  int b = blockIdx.x >> 6;
  int myTok = tokBase + w * 16 + lr;

  // ---- phase 1: q^T = W_q^T @ x^T  (C[d][token]; d spread over kg+regs)
  // B-frags: x rows (token = lr within wave's 16)
  short8_t bx[4];
  {
    const float* xp = x + (size_t)myTok * 128 + kg * 8;
#pragma unroll
    for (int kk = 0; kk < 4; ++kk)
      bx[kk] = trunc8(*(const float4*)(xp + kk * 32),
                      *(const float4*)(xp + kk * 32 + 4));
  }

  f32x4 acc[8] = {};  // acc[mf][j]: d = mf*16 + 4*kg + j, tok = lr
#pragma unroll
  for (int kk = 0; kk < 4; ++kk) {
#pragma unroll
    for (int mf = 0; mf < 8; ++mf) {
      // A-frag: W_q^T row (channel) = mf*16+lr, k-chunk kk*32+kg*8 (L1-hot)
      short8_t aq = *(const short8_t*)(wT + (size_t)(mf * 16 + lr) * 128 + kk * 32 + kg * 8);
      acc[mf] = __builtin_amdgcn_mfma_f32_16x16x32_bf16(aq, bx[kk], acc[mf], 0, 0, 0);
    }
  }

  // ---- softmax over d per head: 8 in-reg exp+add, TWO shuffles (xor16,32)
#pragma unroll
  for (int h = 0; h < 4; ++h) {
    float s = 0;
#pragma unroll
    for (int mh = 0; mh < 2; ++mh) {
      int mf = 2 * h + mh;
#pragma unroll
      for (int j = 0; j < 4; ++j) {
        acc[mf][j] = __expf(acc[mf][j]);
        s += acc[mf][j];
      }
    }
    s += __shfl_xor(s, 16, 64);
    s += __shfl_xor(s, 32, 64);
    float inv = SCALE_Q / s;
#pragma unroll
    for (int mh = 0; mh < 2; ++mh) {
      int mf = 2 * h + mh;
      uint2 p;
      p.x = pack2(acc[mf][0] * inv, acc[mf][1] * inv);
      p.y = pack2(acc[mf][2] * inv, acc[mf][3] * inv);
      // row = my token, col = d = mf*16 + 4*kg (+j packed)
      *(uint2*)&QS[w * 16 + lr][mf * 16 + kg * 4] = p;
    }
  }
  // no barrier: wave reads back only its own rows (lgkmcnt orders same-wave LDS)

  // ---- phase 2: out = qs @ W_eff[b]  (normal orientation, C[token][c])
  const unsigned short* wb = weffT + (size_t)b * 16384;
  f32x4 acc2[8] = {};  // acc2[nf][j]: tok = tokBase+w*16+4*kg+j, c = nf*16+lr
#pragma unroll
  for (int kk = 0; kk < 4; ++kk) {
    short8_t aq2 = *(const short8_t*)&QS[w * 16 + lr][kk * 32 + kg * 8];
#pragma unroll
    for (int nf = 0; nf < 8; ++nf) {
      short8_t bw = *(const short8_t*)(wb + (size_t)(nf * 16 + lr) * 128 + kk * 32 + kg * 8);
      acc2[nf] = __builtin_amdgcn_mfma_f32_16x16x32_bf16(aq2, bw, acc2[nf], 0, 0, 0);
    }
  }

  // ---- bias + LayerNorm + store
  float bo[8], gl[8], bl[8];
#pragma unroll
  for (int nf = 0; nf < 8; ++nf) {
    int c = nf * 16 + lr;
    bo[nf] = b_out[c]; gl[nf] = g_ln[c]; bl[nf] = b_ln[c];
  }
#pragma unroll
  for (int nf = 0; nf < 8; ++nf)
#pragma unroll
    for (int j = 0; j < 4; ++j) acc2[nf][j] += bo[nf];

  float s[4] = {0, 0, 0, 0}, q[4] = {0, 0, 0, 0};
#pragma unroll
  for (int nf = 0; nf < 8; ++nf)
#pragma unroll
    for (int j = 0; j < 4; ++j) {
      float v = acc2[nf][j];
      s[j] += v; q[j] += v * v;
    }
#pragma unroll
  for (int j = 0; j < 4; ++j) {
#pragma unroll
    for (int d = 1; d < 16; d <<= 1) {
      s[j] += __shfl_xor(s[j], d, 64);
      q[j] += __shfl_xor(q[j], d, 64);
    }
  }
#pragma unroll
  for (int j = 0; j < 4; ++j) {
    float mean = s[j] * (1.0f / 128.0f);
    float var = q[j] * (1.0f / 128.0f) - mean * mean;
    float rstd = rsqrtf(var + EPS_LN);
    size_t ro = (size_t)(tokBase + w * 16 + kg * 4 + j) * 128;
#pragma unroll
    for (int nf = 0; nf < 8; ++nf)
      out[ro + nf * 16 + lr] = (acc2[nf][j] - mean) * rstd * gl[nf] + bl[nf];
  }
}

extern "C" void kernel_launch(void* const* d_in, const int* in_sizes, int n_in,
                              void* d_out, int out_size, void* d_ws, size_t ws_size,
                              hipStream_t stream) {
  const float* x     = (const float*)d_in[0];
  const float* w_qkv = (const float*)d_in[1];
  const float* w_out = (const float*)d_in[2];
  const float* b_out = (const float*)d_in[3];
  const float* g_ln  = (const float*)d_in[4];
  const float* b_ln  = (const float*)d_in[5];
  float* out = (float*)d_out;

  char* ws = (char*)d_ws;
  unsigned short* wqkvT = (unsigned short*)(ws + 0);                  // 96 KB
  float* ctxp           = (float*)(ws + 131072);                     // 8 MB [512][4][32][32]
  float* ksump          = (float*)(ws + 131072 + 8388608);           // 256 KB [512][128]
  unsigned short* weffT = (unsigned short*)(ws + 131072 + 8388608 + 262144);  // 512 KB

  k_transpose_wqkv<<<96, 256, 0, stream>>>(w_qkv, wqkvT);
  k_kv_ctx<<<512, 256, 0, stream>>>(x, wqkvT, ctxp, ksump);
  k_weff64<<<64, 256, 0, stream>>>(ctxp, ksump, w_out, weffT);
  k_qout2<<<1024, 256, 0, stream>>>(x, wqkvT, weffT, b_out, g_ln, b_ln, out);
}

// Round 7
// 61.501 us; speedup vs baseline: 1.1496x; 1.1496x over previous
//
#include <hip/hip_runtime.h>
#include <hip/hip_bf16.h>
#include <cstddef>
#include <cstdint>

// LinearAttention fused pipeline, MI355X gfx950.
// x:[16,64,64,128] f32, w_qkv:[128,384], w_out:[128,128], b_out/g_ln/b_ln:[128]
// Pipeline (4 kernels):
//   K1 k_transpose_wqkv: w_qkv -> w_qkv^T bf16
//   K2 k_qkv_mega: per 128-token tile, x loaded ONCE (batched 16B loads,
//      16 in flight/lane): q,k,v GEMMs (B-frags batch-gathered from L2);
//      k->exp, v -> LDS transpose; q -> softmax(d)*scale -> qs bf16;
//      ONE barrier; per-head ctx[32][32] partial MFMA + ksum via MFMA(ones).
//   K3 k_weff64: per (b,h): reduce ctx partials, ctxn=ctx/ksum,
//      W_eff^T[b][c][h*32+d] = sum_e ctxn[d][e]*wout[h*32+e][c]  (bf16)
//   K4 k_out_ln: out = LN( qs @ W_eff[b] + b_out ), no LDS/barriers (ROOFLINE:
//      50MB traffic ~ 9us; do not touch).
// Lessons: R4~R5 => weight LDS-staging vs L2 gather is NEUTRAL; R6 => fusing
// q into out_ln regressed; R7 thesis: latency-bound from too few bytes in
// flight (Little's law) + x read twice — batch loads, read x once.

typedef __attribute__((ext_vector_type(8))) short short8_t;
typedef __attribute__((ext_vector_type(4))) float f32x4;

#define SCALE_Q 0.17677669529663687f
#define EPS_LN 1e-5f

__device__ __forceinline__ unsigned short f2bf(float f) {
  union { float f; unsigned u; } v; v.f = f;
  unsigned r = (v.u + 0x7FFFu + ((v.u >> 16) & 1u)) >> 16;
  return (unsigned short)r;
}
__device__ __forceinline__ float bf2f(unsigned short u) {
  union { float f; unsigned u; } v; v.u = ((unsigned)u) << 16;
  return v.f;
}

// pack 8 f32 -> 8 bf16 by truncation: 4x v_perm_b32
__device__ __forceinline__ short8_t trunc8(float4 lo, float4 hi) {
  union { float4 f; unsigned u[4]; } a, b;
  union { unsigned u[4]; short8_t s; } r;
  a.f = lo; b.f = hi;
  r.u[0] = __builtin_amdgcn_perm(a.u[1], a.u[0], 0x07060302);
  r.u[1] = __builtin_amdgcn_perm(a.u[3], a.u[2], 0x07060302);
  r.u[2] = __builtin_amdgcn_perm(b.u[1], b.u[0], 0x07060302);
  r.u[3] = __builtin_amdgcn_perm(b.u[3], b.u[2], 0x07060302);
  return r.s;
}

// ---------------- K1: transpose + bf16 convert w_qkv [128][384] -> [384][128]
__global__ void k_transpose_wqkv(const float* __restrict__ w,
                                 unsigned short* __restrict__ wT) {
  int c = blockIdx.x * 4 + (threadIdx.x >> 6);   // 96 blocks -> c < 384
  int l = threadIdx.x & 63;
  float f0 = w[(size_t)(2 * l) * 384 + c];
  float f1 = w[(size_t)(2 * l + 1) * 384 + c];
  unsigned p = (unsigned)f2bf(f0) | ((unsigned)f2bf(f1) << 16);
  ((unsigned*)(wT + (size_t)c * 128))[l] = p;
}

// ---------------- K2: mega q+k+v + ctx partial + ksum + qs
// grid 512 (one per 128-token tile), 4 waves, ONE barrier.
__global__ __launch_bounds__(256, 2)
void k_qkv_mega(const float* __restrict__ x, const unsigned short* __restrict__ wT,
                float* __restrict__ ctxp, float* __restrict__ ksump,
                unsigned short* __restrict__ qs) {
  __shared__ short ekT[128][132];  // exp(k) transposed [channel d][token]
  __shared__ short vT[128][132];   // v transposed [channel e][token]

  int tid = threadIdx.x;
  int rb = blockIdx.x;
  int rowBase = rb * 128;
  int lane = tid & 63;
  int wv = tid >> 6;
  int wr = wv >> 1, wc = wv & 1;
  int lr = lane & 15;
  int kg = lane >> 4;

  // ---- x A-fragments: batch 16x 16B loads in flight per half, then trunc
  short8_t abf[4][4];  // [kk][mf]
  {
    const float* ap = x + (size_t)(rowBase + wr * 64 + lr) * 128 + kg * 8;
#pragma unroll
    for (int half = 0; half < 2; ++half) {
      float4 xr[16];
#pragma unroll
      for (int mh = 0; mh < 2; ++mh) {
        const float* r = ap + (size_t)(half * 2 + mh) * 16 * 128;
#pragma unroll
        for (int kk = 0; kk < 4; ++kk) {
          xr[mh * 8 + kk * 2]     = *(const float4*)(r + kk * 32);
          xr[mh * 8 + kk * 2 + 1] = *(const float4*)(r + kk * 32 + 4);
        }
      }
#pragma unroll
      for (int mh = 0; mh < 2; ++mh)
#pragma unroll
        for (int kk = 0; kk < 4; ++kk)
          abf[kk][half * 2 + mh] = trunc8(xr[mh * 8 + kk * 2], xr[mh * 8 + kk * 2 + 1]);
    }
  }

  const unsigned short* wq = wT;
  const unsigned short* wk = wT + 16384;
  const unsigned short* wvv = wT + 32768;
  int bRow[4];
#pragma unroll
  for (int nf = 0; nf < 4; ++nf) bRow[nf] = (wc * 64 + nf * 16 + lr) * 128;

  uint2 ekp[4][4], vp[4][4];

  // ---- k GEMM: batch all 16 B-frags, then MFMAs; epilogue exp->pack
  {
    short8_t bfr[4][4];
#pragma unroll
    for (int kk = 0; kk < 4; ++kk)
#pragma unroll
      for (int nf = 0; nf < 4; ++nf)
        bfr[kk][nf] = *(const short8_t*)(wk + bRow[nf] + kk * 32 + kg * 8);
    f32x4 acc[4][4] = {};
#pragma unroll
    for (int kk = 0; kk < 4; ++kk)
#pragma unroll
      for (int mf = 0; mf < 4; ++mf)
#pragma unroll
        for (int nf = 0; nf < 4; ++nf)
          acc[mf][nf] = __builtin_amdgcn_mfma_f32_16x16x32_bf16(abf[kk][mf], bfr[kk][nf], acc[mf][nf], 0, 0, 0);
#pragma unroll
    for (int mf = 0; mf < 4; ++mf)
#pragma unroll
      for (int nf = 0; nf < 4; ++nf) {
        unsigned s0 = f2bf(__expf(acc[mf][nf][0])), s1 = f2bf(__expf(acc[mf][nf][1]));
        unsigned s2 = f2bf(__expf(acc[mf][nf][2])), s3 = f2bf(__expf(acc[mf][nf][3]));
        ekp[mf][nf].x = s0 | (s1 << 16);
        ekp[mf][nf].y = s2 | (s3 << 16);
      }
  }
  // ---- v GEMM
  {
    short8_t bfr[4][4];
#pragma unroll
    for (int kk = 0; kk < 4; ++kk)
#pragma unroll
      for (int nf = 0; nf < 4; ++nf)
        bfr[kk][nf] = *(const short8_t*)(wvv + bRow[nf] + kk * 32 + kg * 8);
    f32x4 acc[4][4] = {};
#pragma unroll
    for (int kk = 0; kk < 4; ++kk)
#pragma unroll
      for (int mf = 0; mf < 4; ++mf)
#pragma unroll
        for (int nf = 0; nf < 4; ++nf)
          acc[mf][nf] = __builtin_amdgcn_mfma_f32_16x16x32_bf16(abf[kk][mf], bfr[kk][nf], acc[mf][nf], 0, 0, 0);
#pragma unroll
    for (int mf = 0; mf < 4; ++mf)
#pragma unroll
      for (int nf = 0; nf < 4; ++nf) {
        unsigned s0 = f2bf(acc[mf][nf][0]), s1 = f2bf(acc[mf][nf][1]);
        unsigned s2 = f2bf(acc[mf][nf][2]), s3 = f2bf(acc[mf][nf][3]);
        vp[mf][nf].x = s0 | (s1 << 16);
        vp[mf][nf].y = s2 | (s3 << 16);
      }
  }

  // ---- transposed LDS writes (no prior LDS use -> no barrier needed before)
#pragma unroll
  for (int mf = 0; mf < 4; ++mf) {
    int t0 = wr * 64 + mf * 16 + kg * 4;  // 4 consecutive tokens
#pragma unroll
    for (int nf = 0; nf < 4; ++nf) {
      int col = wc * 64 + nf * 16 + lr;
      *(uint2*)&ekT[col][t0] = ekp[mf][nf];
      *(uint2*)&vT[col][t0] = vp[mf][nf];
    }
  }

  // ---- q GEMM + softmax over d + qs stores (fills time before barrier;
  //      2B stores drain during barrier/ctx phase)
  {
    short8_t bfr[4][4];
#pragma unroll
    for (int kk = 0; kk < 4; ++kk)
#pragma unroll
      for (int nf = 0; nf < 4; ++nf)
        bfr[kk][nf] = *(const short8_t*)(wq + bRow[nf] + kk * 32 + kg * 8);
    f32x4 qacc[4][4] = {};
#pragma unroll
    for (int kk = 0; kk < 4; ++kk)
#pragma unroll
      for (int mf = 0; mf < 4; ++mf)
#pragma unroll
        for (int nf = 0; nf < 4; ++nf)
          qacc[mf][nf] = __builtin_amdgcn_mfma_f32_16x16x32_bf16(abf[kk][mf], bfr[kk][nf], qacc[mf][nf], 0, 0, 0);

#pragma unroll
    for (int hg = 0; hg < 2; ++hg) {
#pragma unroll
      for (int mf = 0; mf < 4; ++mf) {
#pragma unroll
        for (int j = 0; j < 4; ++j) {
          float e0 = __expf(qacc[mf][hg * 2][j]);
          float e1 = __expf(qacc[mf][hg * 2 + 1][j]);
          float s = e0 + e1;
#pragma unroll
          for (int d = 1; d < 16; d <<= 1) s += __shfl_xor(s, d, 64);
          float inv = SCALE_Q / s;
          int tok = rowBase + wr * 64 + mf * 16 + kg * 4 + j;
          int hd = wc * 64 + hg * 32 + lr;
          qs[(size_t)tok * 128 + hd] = f2bf(e0 * inv);
          qs[(size_t)tok * 128 + hd + 16] = f2bf(e1 * inv);
        }
      }
    }
  }

  __syncthreads();  // ekT/vT complete (the ONLY barrier)

  // ---- per-head ctx MFMA (wave = head) + ksum via MFMA with ones-vector
  {
    int h = wv;
    union { unsigned u[4]; short8_t s; } ones;
#pragma unroll
    for (int i = 0; i < 4; ++i) ones.u[i] = 0x3F803F80u;  // bf16 1.0 x2

    f32x4 c2[2][2] = {};
    f32x4 ks2[2] = {};
#pragma unroll
    for (int kk = 0; kk < 4; ++kk) {
      short8_t a2[2], b2[2];
#pragma unroll
      for (int m2 = 0; m2 < 2; ++m2)
        a2[m2] = *(const short8_t*)&ekT[h * 32 + m2 * 16 + lr][kk * 32 + kg * 8];
#pragma unroll
      for (int n2 = 0; n2 < 2; ++n2)
        b2[n2] = *(const short8_t*)&vT[h * 32 + n2 * 16 + lr][kk * 32 + kg * 8];
#pragma unroll
      for (int m2 = 0; m2 < 2; ++m2) {
#pragma unroll
        for (int n2 = 0; n2 < 2; ++n2)
          c2[m2][n2] = __builtin_amdgcn_mfma_f32_16x16x32_bf16(a2[m2], b2[n2], c2[m2][n2], 0, 0, 0);
        ks2[m2] = __builtin_amdgcn_mfma_f32_16x16x32_bf16(a2[m2], ones.s, ks2[m2], 0, 0, 0);
      }
    }
    float* cp = ctxp + ((size_t)rb * 4 + h) * 1024;
#pragma unroll
    for (int m2 = 0; m2 < 2; ++m2)
#pragma unroll
      for (int n2 = 0; n2 < 2; ++n2)
#pragma unroll
        for (int j = 0; j < 4; ++j)
          cp[(m2 * 16 + kg * 4 + j) * 32 + n2 * 16 + lr] = c2[m2][n2][j];
    if (lr == 0) {  // every col of ks2 identical; col 0 lanes store
#pragma unroll
      for (int m2 = 0; m2 < 2; ++m2)
#pragma unroll
        for (int j = 0; j < 4; ++j)
          ksump[(size_t)rb * 128 + h * 32 + m2 * 16 + kg * 4 + j] = ks2[m2][j];
    }
  }
}

// ---------------- K3: per (b,h) reduce partials + build W_eff^T cols
// grid 64. weffT[b][c][h*32+d] = sum_e (ctx[d][e]/ksum[d]) * wout[h*32+e][c]
__global__ __launch_bounds__(256, 4)
void k_weff64(const float* __restrict__ ctxp, const float* __restrict__ ksump,
              const float* __restrict__ wout, unsigned short* __restrict__ weffT) {
  __shared__ float wo[32][128];  // wout rows h*32+e
  __shared__ float cn[32][32];   // ctxn[d][e]
  __shared__ float ksh[32];
  int tid = threadIdx.x;
  int b = blockIdx.x >> 2, h = blockIdx.x & 3;

#pragma unroll
  for (int i = 0; i < 16; ++i) {
    int idx = i * 256 + tid;
    int e = idx >> 7, jj = idx & 127;
    wo[e][jj] = wout[(h * 32 + e) * 128 + jj];
  }
  if (tid < 32) {
    float s = 0;
    for (int c = 0; c < 32; ++c)
      s += ksump[(size_t)(b * 32 + c) * 128 + h * 32 + tid];
    ksh[tid] = s;
  }
  __syncthreads();
#pragma unroll
  for (int i = 0; i < 4; ++i) {
    int idx = i * 256 + tid;
    int d = idx >> 5;
    float s = 0;
    for (int c = 0; c < 32; ++c)
      s += ctxp[((size_t)(b * 32 + c) * 4 + h) * 1024 + idx];
    cn[d][idx & 31] = s / ksh[d];
  }
  __syncthreads();

  int j = tid >> 1, dg = tid & 1;
  unsigned short acc16[16];
#pragma unroll
  for (int dd = 0; dd < 16; ++dd) {
    int d = dg * 16 + dd;
    float s = 0;
#pragma unroll
    for (int e = 0; e < 32; ++e) s += cn[d][e] * wo[e][j];
    acc16[dd] = f2bf(s);
  }
  unsigned short* outp = weffT + (size_t)b * 16384 + j * 128 + h * 32 + dg * 16;
  *(short8_t*)outp = *(short8_t*)&acc16[0];
  *(short8_t*)(outp + 8) = *(short8_t*)&acc16[8];
}

// ---------------- K4: out = LN( qs @ W_eff[b] + b_out ) — at traffic roofline
__global__ __launch_bounds__(256, 2)
void k_out_ln(const unsigned short* __restrict__ qs, const unsigned short* __restrict__ weffT,
              const float* __restrict__ b_out, const float* __restrict__ g_ln,
              const float* __restrict__ b_ln, float* __restrict__ out) {
  int tid = threadIdx.x;
  int rowBase = blockIdx.x * 128;
  int b = rowBase >> 12;
  int lane = tid & 63;
  int w = tid >> 6;
  int lr = lane & 15;
  int kg = lane >> 4;

  const unsigned short* bb = weffT + (size_t)b * 16384;

  short8_t a[2][4];  // [mf][kk]
  {
    const unsigned short* ap = qs + (size_t)(rowBase + w * 32 + lr) * 128 + kg * 8;
#pragma unroll
    for (int mf = 0; mf < 2; ++mf)
#pragma unroll
      for (int kk = 0; kk < 4; ++kk)
        a[mf][kk] = *(const short8_t*)(ap + (size_t)mf * 16 * 128 + kk * 32);
  }

  f32x4 acc[2][8] = {};
#pragma unroll
  for (int kk = 0; kk < 4; ++kk) {
    short8_t bf[8];
#pragma unroll
    for (int nf = 0; nf < 8; ++nf)
      bf[nf] = *(const short8_t*)(bb + (size_t)(nf * 16 + lr) * 128 + kk * 32 + kg * 8);
#pragma unroll
    for (int mf = 0; mf < 2; ++mf)
#pragma unroll
      for (int nf = 0; nf < 8; ++nf)
        acc[mf][nf] = __builtin_amdgcn_mfma_f32_16x16x32_bf16(a[mf][kk], bf[nf], acc[mf][nf], 0, 0, 0);
  }

  float bo[8], gl[8], bl[8];
#pragma unroll
  for (int nf = 0; nf < 8; ++nf) {
    int c = nf * 16 + lr;
    bo[nf] = b_out[c]; gl[nf] = g_ln[c]; bl[nf] = b_ln[c];
  }
#pragma unroll
  for (int mf = 0; mf < 2; ++mf)
#pragma unroll
    for (int nf = 0; nf < 8; ++nf)
#pragma unroll
      for (int j = 0; j < 4; ++j) acc[mf][nf][j] += bo[nf];

#pragma unroll
  for (int mf = 0; mf < 2; ++mf) {
    float s[4] = {0, 0, 0, 0}, q[4] = {0, 0, 0, 0};
#pragma unroll
    for (int nf = 0; nf < 8; ++nf)
#pragma unroll
      for (int j = 0; j < 4; ++j) {
        float v = acc[mf][nf][j];
        s[j] += v; q[j] += v * v;
      }
#pragma unroll
    for (int j = 0; j < 4; ++j) {
#pragma unroll
      for (int d = 1; d < 16; d <<= 1) {
        s[j] += __shfl_xor(s[j], d, 64);
        q[j] += __shfl_xor(q[j], d, 64);
      }
    }
#pragma unroll
    for (int j = 0; j < 4; ++j) {
      float mean = s[j] * (1.0f / 128.0f);
      float var = q[j] * (1.0f / 128.0f) - mean * mean;
      float rstd = rsqrtf(var + EPS_LN);
      size_t ro = (size_t)(rowBase + w * 32 + mf * 16 + kg * 4 + j) * 128;
#pragma unroll
      for (int nf = 0; nf < 8; ++nf)
        out[ro + nf * 16 + lr] = (acc[mf][nf][j] - mean) * rstd * gl[nf] + bl[nf];
    }
  }
}

extern "C" void kernel_launch(void* const* d_in, const int* in_sizes, int n_in,
                              void* d_out, int out_size, void* d_ws, size_t ws_size,
                              hipStream_t stream) {
  const float* x     = (const float*)d_in[0];
  const float* w_qkv = (const float*)d_in[1];
  const float* w_out = (const float*)d_in[2];
  const float* b_out = (const float*)d_in[3];
  const float* g_ln  = (const float*)d_in[4];
  const float* b_ln  = (const float*)d_in[5];
  float* out = (float*)d_out;

  char* ws = (char*)d_ws;
  unsigned short* wqkvT = (unsigned short*)(ws + 0);                  // 96 KB
  float* ctxp           = (float*)(ws + 131072);                     // 8 MB [512][4][32][32]
  float* ksump          = (float*)(ws + 131072 + 8388608);           // 256 KB [512][128]
  unsigned short* weffT = (unsigned short*)(ws + 131072 + 8388608 + 262144);  // 512 KB
  unsigned short* qs    = (unsigned short*)(ws + 131072 + 8388608 + 262144 + 524288); // 16 MB

  k_transpose_wqkv<<<96, 256, 0, stream>>>(w_qkv, wqkvT);
  k_qkv_mega<<<512, 256, 0, stream>>>(x, wqkvT, ctxp, ksump, qs);
  k_weff64<<<64, 256, 0, stream>>>(ctxp, ksump, w_out, weffT);
  k_out_ln<<<512, 256, 0, stream>>>(qs, weffT, b_out, g_ln, b_ln, out);
}